// Round 2
// baseline (1153.275 us; speedup 1.0000x reference)
//
#include <hip/hip_runtime.h>
#include <hip/hip_bf16.h>
#include <stdint.h>

// Problem constants (QuantizedLinear_15985868276124)
#define IN_F   4096
#define OUT_F  11008
#define M_TOK  8192                  // 4 * 2048 tokens
#define NGRP   (OUT_F * (IN_F / 8)) // 5,636,096 groups of 8 weights

typedef __attribute__((ext_vector_type(8))) short short8;
typedef __attribute__((ext_vector_type(4))) float f32x4;

// ---------- helpers ----------

__device__ __forceinline__ unsigned short bf16_rne(float f) {
    union { float f; uint32_t u; } v; v.f = f;
    uint32_t r = v.u + 0x7FFFu + ((v.u >> 16) & 1u); // round-to-nearest-even
    return (unsigned short)(r >> 16);
}

__device__ __forceinline__ void gload_lds16(const void* g, void* l) {
    __builtin_amdgcn_global_load_lds(
        (const __attribute__((address_space(1))) void*)g,
        (__attribute__((address_space(3))) void*)l,
        16 /*bytes, literal*/, 0, 0);
}

// ---------- kernel 1: dequantize W -> bf16 [OUT_F][IN_F] ----------
// codes:      [no=11008][ni=512][2] int32
// codebooks:  [2][256][1][8] fp32  (16 KB -> LDS)
// scales:     [no] fp32
__global__ __launch_bounds__(256) void k_dequant(
        const int* __restrict__ codes,
        const float* __restrict__ codebooks,
        const float* __restrict__ scales,
        unsigned short* __restrict__ Wq) {
    __shared__ float cb[4096]; // [2][256][8]
    int tid = threadIdx.x;
    const float4* cbg = (const float4*)codebooks;
    float4* cbl = (float4*)cb;
#pragma unroll
    for (int i = 0; i < 4; ++i) cbl[tid + i * 256] = cbg[tid + i * 256];
    __syncthreads();

    int gidx = blockIdx.x * 256 + tid;      // group index in [0, NGRP)
    int o = gidx >> 9;                      // / 512
    float s = scales[o];
    int2 c = ((const int2*)codes)[gidx];

    const float4* e0 = (const float4*)&cb[c.x * 8];
    const float4* e1 = (const float4*)&cb[2048 + c.y * 8];
    float4 a0 = e0[0], a1 = e0[1];
    float4 b0 = e1[0], b1 = e1[1];

    float r[8];
    r[0] = (a0.x + b0.x) * s; r[1] = (a0.y + b0.y) * s;
    r[2] = (a0.z + b0.z) * s; r[3] = (a0.w + b0.w) * s;
    r[4] = (a1.x + b1.x) * s; r[5] = (a1.y + b1.y) * s;
    r[6] = (a1.z + b1.z) * s; r[7] = (a1.w + b1.w) * s;

    uint4 pk;
    pk.x = (uint32_t)bf16_rne(r[0]) | ((uint32_t)bf16_rne(r[1]) << 16);
    pk.y = (uint32_t)bf16_rne(r[2]) | ((uint32_t)bf16_rne(r[3]) << 16);
    pk.z = (uint32_t)bf16_rne(r[4]) | ((uint32_t)bf16_rne(r[5]) << 16);
    pk.w = (uint32_t)bf16_rne(r[6]) | ((uint32_t)bf16_rne(r[7]) << 16);
    *(uint4*)(Wq + (size_t)gidx * 8) = pk;
}

// ---------- kernel 2: x fp32 -> bf16 ----------
__global__ __launch_bounds__(256) void k_cvt(
        const float* __restrict__ x, unsigned short* __restrict__ Xq) {
    size_t i = ((size_t)blockIdx.x * 256 + threadIdx.x) * 8;
    float4 v0 = *(const float4*)(x + i);
    float4 v1 = *(const float4*)(x + i + 4);
    uint4 pk;
    pk.x = (uint32_t)bf16_rne(v0.x) | ((uint32_t)bf16_rne(v0.y) << 16);
    pk.y = (uint32_t)bf16_rne(v0.z) | ((uint32_t)bf16_rne(v0.w) << 16);
    pk.z = (uint32_t)bf16_rne(v1.x) | ((uint32_t)bf16_rne(v1.y) << 16);
    pk.w = (uint32_t)bf16_rne(v1.z) | ((uint32_t)bf16_rne(v1.w) << 16);
    *(uint4*)(Xq + i) = pk;
}

// ---------- kernel 3: GEMM C[M_TOK][OUT_F] = Xq * Wq^T + bias ----------
// m97 structure: 128x128 tile, BK=64, 4 waves (2x2 of 64x64),
// mfma_f32_16x16x32_bf16, global_load_lds width-16 staging.
__global__ __launch_bounds__(256) void k_gemm(
        const unsigned short* __restrict__ A,   // [M_TOK][IN_F] bf16
        const unsigned short* __restrict__ B,   // [OUT_F][IN_F] bf16 (B^T layout)
        const float* __restrict__ bias,
        float* __restrict__ out) {
    __shared__ unsigned short lA[128 * 64];
    __shared__ unsigned short lB[128 * 64];

    int tid = threadIdx.x;
    int l = tid & 63;
    int w = tid >> 6;          // wave 0..3
    int wm = w >> 1, wn = w & 1;

    int rowBase = blockIdx.y * 128;   // token rows
    int colBase = blockIdx.x * 128;   // output cols

    // staging addressing: wave w covers rows [w*32, w*32+32) of each tile,
    // 4 instructions x (64 lanes x 8 elems) = 8 rows per instruction
    int srow = w * 32 + (l >> 3);
    int scol = (l & 7) * 8;
    const unsigned short* gA = A + (size_t)(rowBase + srow) * IN_F + scol;
    const unsigned short* gB = B + (size_t)(colBase + srow) * IN_F + scol;
    unsigned short* lA_base = &lA[(w * 32) * 64]; // HW adds lane*16B
    unsigned short* lB_base = &lB[(w * 32) * 64];

    int frow = l & 15;
    int fk = (l >> 4) * 8;

    f32x4 acc[4][4] = {};

    for (int kt = 0; kt < IN_F; kt += 64) {
#pragma unroll
        for (int i = 0; i < 4; ++i) {
            gload_lds16(gA + (size_t)i * 8 * IN_F + kt, lA_base + i * 8 * 64);
            gload_lds16(gB + (size_t)i * 8 * IN_F + kt, lB_base + i * 8 * 64);
        }
        __syncthreads();
#pragma unroll
        for (int kk = 0; kk < 2; ++kk) {
            short8 af[4], bfv[4];
#pragma unroll
            for (int m = 0; m < 4; ++m)
                af[m] = *(const short8*)&lA[(wm * 64 + m * 16 + frow) * 64 + kk * 32 + fk];
#pragma unroll
            for (int n = 0; n < 4; ++n)
                bfv[n] = *(const short8*)&lB[(wn * 64 + n * 16 + frow) * 64 + kk * 32 + fk];
#pragma unroll
            for (int m = 0; m < 4; ++m)
#pragma unroll
                for (int n = 0; n < 4; ++n)
                    acc[m][n] = __builtin_amdgcn_mfma_f32_16x16x32_bf16(
                        af[m], bfv[n], acc[m][n], 0, 0, 0);
        }
        __syncthreads();
    }

    // epilogue: C/D layout col = lane&15, row = (lane>>4)*4 + j
#pragma unroll
    for (int n = 0; n < 4; ++n) {
        int gcol = colBase + wn * 64 + n * 16 + (l & 15);
        float bv = bias[gcol];
#pragma unroll
        for (int m = 0; m < 4; ++m) {
            int grow0 = rowBase + wm * 64 + m * 16 + (l >> 4) * 4;
#pragma unroll
            for (int j = 0; j < 4; ++j)
                out[(size_t)(grow0 + j) * OUT_F + gcol] = acc[m][n][j] + bv;
        }
    }
}

// ---------- launch ----------
extern "C" void kernel_launch(void* const* d_in, const int* in_sizes, int n_in,
                              void* d_out, int out_size, void* d_ws, size_t ws_size,
                              hipStream_t stream) {
    const float* x         = (const float*)d_in[0];
    const int*   codes     = (const int*)d_in[1];
    const float* codebooks = (const float*)d_in[2];
    const float* scales    = (const float*)d_in[3];
    const float* bias      = (const float*)d_in[4];
    float* out = (float*)d_out;

    // workspace layout: Wq bf16 [OUT_F][IN_F] then Xq bf16 [M_TOK][IN_F]
    // needs 90,177,536 + 67,108,864 = 157,286,400 bytes
    unsigned short* Wq = (unsigned short*)d_ws;
    unsigned short* Xq = (unsigned short*)((char*)d_ws + (size_t)OUT_F * IN_F * 2);

    k_dequant<<<NGRP / 256, 256, 0, stream>>>(codes, codebooks, scales, Wq);
    k_cvt<<<(M_TOK * IN_F / 8) / 256, 256, 0, stream>>>(x, Xq);
    k_gemm<<<dim3(OUT_F / 128, M_TOK / 128), 256, 0, stream>>>(Xq, Wq, bias, out);
}

// Round 4
// 900.212 us; speedup vs baseline: 1.2811x; 1.2811x over previous
//
#include <hip/hip_runtime.h>
#include <hip/hip_bf16.h>
#include <stdint.h>

// Problem constants (QuantizedLinear_15985868276124)
#define IN_F   4096
#define OUT_F  11008
#define M_TOK  8192                  // 4 * 2048 tokens
#define NGRP   (OUT_F * (IN_F / 8)) // 5,636,096 groups of 8 weights

typedef __attribute__((ext_vector_type(8))) short short8;
typedef __attribute__((ext_vector_type(4))) float f32x4;

// ---------- helpers ----------

__device__ __forceinline__ unsigned short bf16_rne(float f) {
    union { float f; uint32_t u; } v; v.f = f;
    uint32_t r = v.u + 0x7FFFu + ((v.u >> 16) & 1u); // round-to-nearest-even
    return (unsigned short)(r >> 16);
}

// ---------- kernel 1: dequantize W -> bf16 [OUT_F][IN_F] ----------
__global__ __launch_bounds__(256) void k_dequant(
        const int* __restrict__ codes,
        const float* __restrict__ codebooks,
        const float* __restrict__ scales,
        unsigned short* __restrict__ Wq) {
    __shared__ float cb[4096]; // [2][256][8]
    int tid = threadIdx.x;
    const float4* cbg = (const float4*)codebooks;
    float4* cbl = (float4*)cb;
#pragma unroll
    for (int i = 0; i < 4; ++i) cbl[tid + i * 256] = cbg[tid + i * 256];
    __syncthreads();

    int gidx = blockIdx.x * 256 + tid;      // group index in [0, NGRP)
    int o = gidx >> 9;                      // / 512
    float s = scales[o];
    int2 c = ((const int2*)codes)[gidx];

    const float4* e0 = (const float4*)&cb[c.x * 8];
    const float4* e1 = (const float4*)&cb[2048 + c.y * 8];
    float4 a0 = e0[0], a1 = e0[1];
    float4 b0 = e1[0], b1 = e1[1];

    float r[8];
    r[0] = (a0.x + b0.x) * s; r[1] = (a0.y + b0.y) * s;
    r[2] = (a0.z + b0.z) * s; r[3] = (a0.w + b0.w) * s;
    r[4] = (a1.x + b1.x) * s; r[5] = (a1.y + b1.y) * s;
    r[6] = (a1.z + b1.z) * s; r[7] = (a1.w + b1.w) * s;

    uint4 pk;
    pk.x = (uint32_t)bf16_rne(r[0]) | ((uint32_t)bf16_rne(r[1]) << 16);
    pk.y = (uint32_t)bf16_rne(r[2]) | ((uint32_t)bf16_rne(r[3]) << 16);
    pk.z = (uint32_t)bf16_rne(r[4]) | ((uint32_t)bf16_rne(r[5]) << 16);
    pk.w = (uint32_t)bf16_rne(r[6]) | ((uint32_t)bf16_rne(r[7]) << 16);
    *(uint4*)(Wq + (size_t)gidx * 8) = pk;
}

// ---------- kernel 2: x fp32 -> bf16 ----------
__global__ __launch_bounds__(256) void k_cvt(
        const float* __restrict__ x, unsigned short* __restrict__ Xq) {
    size_t i = ((size_t)blockIdx.x * 256 + threadIdx.x) * 8;
    float4 v0 = *(const float4*)(x + i);
    float4 v1 = *(const float4*)(x + i + 4);
    uint4 pk;
    pk.x = (uint32_t)bf16_rne(v0.x) | ((uint32_t)bf16_rne(v0.y) << 16);
    pk.y = (uint32_t)bf16_rne(v0.z) | ((uint32_t)bf16_rne(v0.w) << 16);
    pk.z = (uint32_t)bf16_rne(v1.x) | ((uint32_t)bf16_rne(v1.y) << 16);
    pk.w = (uint32_t)bf16_rne(v1.z) | ((uint32_t)bf16_rne(v1.w) << 16);
    *(uint4*)(Xq + i) = pk;
}

// ---------- kernel 3: 256x256 8-phase GEMM  C = Xq * Wq^T + bias ----------
// BM=BN=256, BK=64, 8 waves (2Mx4N), LDS 128 KiB (2 dbuf), T1/T2/T3/T4/T5.

#define BARRIER() asm volatile("s_barrier" ::: "memory")
#define VMW(n)    asm volatile("s_waitcnt vmcnt(" #n ")" ::: "memory")

#define GL16(gp, lp) __builtin_amdgcn_global_load_lds(                        \
    (const __attribute__((address_space(1))) void*)(gp),                      \
    (__attribute__((address_space(3))) void*)(lp), 16, 0, 0)

__global__ __launch_bounds__(512, 2) void k_gemm(
        const unsigned short* __restrict__ A,   // [M_TOK][IN_F] bf16
        const unsigned short* __restrict__ B,   // [OUT_F][IN_F] bf16 (B^T layout)
        const float* __restrict__ bias,
        float* __restrict__ out) {
    __shared__ unsigned short lA[2][256][64];   // 64 KiB
    __shared__ unsigned short lB[2][256][64];   // 64 KiB

    const int tid = threadIdx.x;
    const int l = tid & 63;
    const int w = tid >> 6;            // wave 0..7
    const int wm = w >> 2, wn = w & 3; // 2 x 4 wave grid; wave tile 128x64

    // T1: bijective XCD swizzle. grid 1376 = 8 XCD * (4 row-chunks * 43 cols)
    int lid = blockIdx.x;
    int xcd = lid & 7, j = lid >> 3;   // j in [0,172)
    int bx = j >> 2;                   // col block 0..42 (column-major in chunk)
    int by = (xcd << 2) + (j & 3);     // row block 0..31
    const int rowBase = by * 256;
    const int colBase = bx * 256;

    // ---- staging addressing (T2: swizzle applied on GLOBAL source; LDS linear)
    // instr covers 64 rows: row = c*64 + w*8 + (l>>3); LDS(r,cc)=global(r, cc^(r&7))
    const int srow = w * 8 + (l >> 3);
    const int scol = ((l & 7) ^ ((l >> 3) & 7)) << 3;   // swizzled element col
    const unsigned short* gA = A + (size_t)(rowBase + srow) * IN_F + scol;
    const unsigned short* gB = B + (size_t)(colBase + srow) * IN_F + scol;
    unsigned short* lAw = &lA[0][w * 8][0];
    unsigned short* lBw = &lB[0][w * 8][0];

#define STAGE(t) do {                                                         \
    const unsigned short* _ga = gA + (t) * 64;                                \
    const unsigned short* _gb = gB + (t) * 64;                                \
    unsigned short* _la = lAw + ((t) & 1) * (256 * 64);                       \
    unsigned short* _lb = lBw + ((t) & 1) * (256 * 64);                       \
    GL16(_ga,                _la);                                            \
    GL16(_ga +  64 * IN_F,   _la +  64 * 64);                                 \
    GL16(_ga + 128 * IN_F,   _la + 128 * 64);                                 \
    GL16(_ga + 192 * IN_F,   _la + 192 * 64);                                 \
    GL16(_gb,                _lb);                                            \
    GL16(_gb +  64 * IN_F,   _lb +  64 * 64);                                 \
    GL16(_gb + 128 * IN_F,   _lb + 128 * 64);                                 \
    GL16(_gb + 192 * IN_F,   _lb + 192 * 64);                                 \
} while (0)

    // ---- fragment reads (swizzled chunk = (kk*4+g) ^ (row&7), row&7 == frow&7)
    const int frow = l & 15, g = l >> 4;
    const int cho0 = ((g ^ (frow & 7)) << 4);
    const int cho1 = (((4 + g) ^ (frow & 7)) << 4);
    const char* rowA = (const char*)&lA[0][wm * 128 + frow][0];
    const char* rowB = (const char*)&lB[0][wn * 64 + frow][0];
#define LDA_(p, m, kk) (*(const short8*)(rowA + (p) * 32768 + (m) * 2048 + ((kk) ? cho1 : cho0)))
#define LDB_(p, n, kk) (*(const short8*)(rowB + (p) * 32768 + (n) * 2048 + ((kk) ? cho1 : cho0)))

    f32x4 acc[8][4] = {};
    short8 ar[4][2], br[4][2];

#define QUAD(M0, N0) do {                                                     \
    __builtin_amdgcn_s_setprio(1);                                            \
    _Pragma("unroll") for (int mm = 0; mm < 4; ++mm)                          \
    _Pragma("unroll") for (int nn = 0; nn < 2; ++nn)                          \
    _Pragma("unroll") for (int kk = 0; kk < 2; ++kk)                          \
        acc[(M0) + mm][(N0) + nn] = __builtin_amdgcn_mfma_f32_16x16x32_bf16(  \
            ar[mm][kk], br[(N0) + nn][kk], acc[(M0) + mm][(N0) + nn], 0, 0, 0);\
    __builtin_amdgcn_s_setprio(0);                                            \
} while (0)

#define PH_A(p) do {                                                          \
    _Pragma("unroll") for (int mm = 0; mm < 4; ++mm) {                        \
        ar[mm][0] = LDA_(p, mm, 0); ar[mm][1] = LDA_(p, mm, 1); }             \
    br[0][0] = LDB_(p, 0, 0); br[0][1] = LDB_(p, 0, 1);                       \
    br[1][0] = LDB_(p, 1, 0); br[1][1] = LDB_(p, 1, 1);                       \
    BARRIER(); QUAD(0, 0); BARRIER();                                         \
} while (0)
#define PH_B(p) do {                                                          \
    br[2][0] = LDB_(p, 2, 0); br[2][1] = LDB_(p, 2, 1);                       \
    br[3][0] = LDB_(p, 3, 0); br[3][1] = LDB_(p, 3, 1);                       \
    BARRIER(); QUAD(0, 2); BARRIER();                                         \
} while (0)
#define PH_C(p) do {                                                          \
    _Pragma("unroll") for (int mm = 0; mm < 4; ++mm) {                        \
        ar[mm][0] = LDA_(p, 4 + mm, 0); ar[mm][1] = LDA_(p, 4 + mm, 1); }     \
    BARRIER(); QUAD(4, 2); BARRIER();                                         \
} while (0)

    // prologue: stage T0 -> buf0, T1 -> buf1; wait T0 (8 loads of T1 in flight)
    STAGE(0); STAGE(1);
    VMW(8); BARRIER();

    // main loop: 2 K-tiles per iteration; tiles 0..63 (IN_F/64)
    for (int i = 0; i < 31; ++i) {
        int t = 2 * i;
        PH_A(0); PH_B(0); PH_C(0);
        STAGE(t + 2); VMW(8); BARRIER(); QUAD(4, 0); BARRIER();   // phase 4
        PH_A(1); PH_B(1); PH_C(1);
        STAGE(t + 3); VMW(8); BARRIER(); QUAD(4, 0); BARRIER();   // phase 8
    }
    // peeled last iteration (tiles 62, 63): no new stages
    PH_A(0); PH_B(0); PH_C(0);
    VMW(0); BARRIER(); QUAD(4, 0); BARRIER();   // drain: T63 must be complete
    PH_A(1); PH_B(1); PH_C(1);
    BARRIER(); QUAD(4, 0);

    // epilogue: C/D layout col = lane&15, row = (lane>>4)*4 + jj
#pragma unroll
    for (int n = 0; n < 4; ++n) {
        int gcol = colBase + wn * 64 + n * 16 + frow;
        float bv = bias[gcol];
#pragma unroll
        for (int m = 0; m < 8; ++m) {
            int grow0 = rowBase + wm * 128 + m * 16 + g * 4;
#pragma unroll
            for (int jj = 0; jj < 4; ++jj)
                out[(size_t)(grow0 + jj) * OUT_F + gcol] = acc[m][n][jj] + bv;
        }
    }
}

// ---------- launch ----------
extern "C" void kernel_launch(void* const* d_in, const int* in_sizes, int n_in,
                              void* d_out, int out_size, void* d_ws, size_t ws_size,
                              hipStream_t stream) {
    const float* x         = (const float*)d_in[0];
    const int*   codes     = (const int*)d_in[1];
    const float* codebooks = (const float*)d_in[2];
    const float* scales    = (const float*)d_in[3];
    const float* bias      = (const float*)d_in[4];
    float* out = (float*)d_out;

    // workspace: Wq bf16 [OUT_F][IN_F], Xq bf16 [M_TOK][IN_F] = 157,286,400 B
    unsigned short* Wq = (unsigned short*)d_ws;
    unsigned short* Xq = (unsigned short*)((char*)d_ws + (size_t)OUT_F * IN_F * 2);

    k_dequant<<<NGRP / 256, 256, 0, stream>>>(codes, codebooks, scales, Wq);
    k_cvt<<<(M_TOK * IN_F / 8) / 256, 256, 0, stream>>>(x, Xq);
    // grid: (8192/256) * (11008/256) = 32 * 43 = 1376 blocks, 512 threads
    k_gemm<<<1376, 512, 0, stream>>>(Xq, Wq, bias, out);
}

// Round 6
// 899.008 us; speedup vs baseline: 1.2828x; 1.0013x over previous
//
#include <hip/hip_runtime.h>
#include <hip/hip_bf16.h>
#include <stdint.h>

// Problem constants (QuantizedLinear_15985868276124)
#define IN_F   4096
#define OUT_F  11008
#define M_TOK  8192                  // 4 * 2048 tokens
#define NGRP   (OUT_F * (IN_F / 8)) // 5,636,096 groups of 8 weights

typedef __attribute__((ext_vector_type(8))) short short8;
typedef __attribute__((ext_vector_type(4))) float f32x4;

// ---------- helpers ----------

__device__ __forceinline__ unsigned short bf16_rne(float f) {
    union { float f; uint32_t u; } v; v.f = f;
    uint32_t r = v.u + 0x7FFFu + ((v.u >> 16) & 1u); // round-to-nearest-even
    return (unsigned short)(r >> 16);
}

// ---------- kernel 1: dequantize W -> bf16 [OUT_F][IN_F] ----------
__global__ __launch_bounds__(256) void k_dequant(
        const int* __restrict__ codes,
        const float* __restrict__ codebooks,
        const float* __restrict__ scales,
        unsigned short* __restrict__ Wq) {
    __shared__ float cb[4096]; // [2][256][8]
    int tid = threadIdx.x;
    const float4* cbg = (const float4*)codebooks;
    float4* cbl = (float4*)cb;
#pragma unroll
    for (int i = 0; i < 4; ++i) cbl[tid + i * 256] = cbg[tid + i * 256];
    __syncthreads();

    int gidx = blockIdx.x * 256 + tid;      // group index in [0, NGRP)
    int o = gidx >> 9;                      // / 512
    float s = scales[o];
    int2 c = ((const int2*)codes)[gidx];

    const float4* e0 = (const float4*)&cb[c.x * 8];
    const float4* e1 = (const float4*)&cb[2048 + c.y * 8];
    float4 a0 = e0[0], a1 = e0[1];
    float4 b0 = e1[0], b1 = e1[1];

    float r[8];
    r[0] = (a0.x + b0.x) * s; r[1] = (a0.y + b0.y) * s;
    r[2] = (a0.z + b0.z) * s; r[3] = (a0.w + b0.w) * s;
    r[4] = (a1.x + b1.x) * s; r[5] = (a1.y + b1.y) * s;
    r[6] = (a1.z + b1.z) * s; r[7] = (a1.w + b1.w) * s;

    uint4 pk;
    pk.x = (uint32_t)bf16_rne(r[0]) | ((uint32_t)bf16_rne(r[1]) << 16);
    pk.y = (uint32_t)bf16_rne(r[2]) | ((uint32_t)bf16_rne(r[3]) << 16);
    pk.z = (uint32_t)bf16_rne(r[4]) | ((uint32_t)bf16_rne(r[5]) << 16);
    pk.w = (uint32_t)bf16_rne(r[6]) | ((uint32_t)bf16_rne(r[7]) << 16);
    *(uint4*)(Wq + (size_t)gidx * 8) = pk;
}

// ---------- kernel 2: x fp32 -> bf16 ----------
__global__ __launch_bounds__(256) void k_cvt(
        const float* __restrict__ x, unsigned short* __restrict__ Xq) {
    size_t i = ((size_t)blockIdx.x * 256 + threadIdx.x) * 8;
    float4 v0 = *(const float4*)(x + i);
    float4 v1 = *(const float4*)(x + i + 4);
    uint4 pk;
    pk.x = (uint32_t)bf16_rne(v0.x) | ((uint32_t)bf16_rne(v0.y) << 16);
    pk.y = (uint32_t)bf16_rne(v0.z) | ((uint32_t)bf16_rne(v0.w) << 16);
    pk.z = (uint32_t)bf16_rne(v1.x) | ((uint32_t)bf16_rne(v1.y) << 16);
    pk.w = (uint32_t)bf16_rne(v1.z) | ((uint32_t)bf16_rne(v1.w) << 16);
    *(uint4*)(Xq + i) = pk;
}

// ---------- kernel 3: 256x256 8-phase GEMM  C = Xq * Wq^T + bias ----------
// BM=BN=256, BK=64, 8 waves (2Mx4N), LDS 128 KiB (2 dbuf).
// Fine interleave, WAR-safe stagger: tile T+2's quarters staged in phases
// D(T), A(T+1), B(T+1), C(T+1); counted VMW(2) at each D phase only.
// Invariant: staging into buf[X] begins only after C-phase closing barrier
// of buf[X]'s previous tenant (all waves' ds_reads drained by their QUADs).

#define BARRIER() asm volatile("s_barrier" ::: "memory")
#define VMW(n)    asm volatile("s_waitcnt vmcnt(" #n ")" ::: "memory")
#define LGKM8()   asm volatile("s_waitcnt lgkmcnt(8)" ::: "memory")

#define GL16(gp, lp) __builtin_amdgcn_global_load_lds(                        \
    (const __attribute__((address_space(1))) void*)(gp),                      \
    (__attribute__((address_space(3))) void*)(lp), 16, 0, 0)

__global__ __launch_bounds__(512, 2) void k_gemm(
        const unsigned short* __restrict__ A,   // [M_TOK][IN_F] bf16
        const unsigned short* __restrict__ B,   // [OUT_F][IN_F] bf16 (B^T layout)
        const float* __restrict__ bias,
        float* __restrict__ out) {
    __shared__ unsigned short lA[2][256][64];   // 64 KiB
    __shared__ unsigned short lB[2][256][64];   // 64 KiB

    const int tid = threadIdx.x;
    const int l = tid & 63;
    const int w = tid >> 6;            // wave 0..7
    const int wm = w >> 2, wn = w & 3; // 2 x 4 wave grid; wave tile 128x64

    // T1: bijective XCD swizzle. grid 1376 = 8 XCD * (4 row-chunks * 43 cols)
    int lid = blockIdx.x;
    int xcd = lid & 7, j = lid >> 3;   // j in [0,172)
    int bx = j >> 2;                   // col block 0..42 (column-major in chunk)
    int by = (xcd << 2) + (j & 3);     // row block 0..31
    const int rowBase = by * 256;
    const int colBase = bx * 256;

    // ---- staging addressing (T2: swizzle applied on GLOBAL source; LDS linear)
    // instr covers 64 rows: row = base + w*8 + (l>>3); LDS(r,cc)=global(r, cc^(r&7))
    const int srow = w * 8 + (l >> 3);
    const int scol = ((l & 7) ^ ((l >> 3) & 7)) << 3;   // swizzled element col
    const unsigned short* gA = A + (size_t)(rowBase + srow) * IN_F + scol;
    const unsigned short* gB = B + (size_t)(colBase + srow) * IN_F + scol;
    unsigned short* lAw = &lA[0][w * 8][0];
    unsigned short* lBw = &lB[0][w * 8][0];

    // stage one quarter: q0/q1 = A rows {0-127, 128-255}; q2/q3 = B same
#define STAGEQ(t, q) do {                                                     \
    const unsigned short* _g = (((q) < 2) ? gA : gB) + (size_t)(t) * 64;      \
    unsigned short* _l = (((q) < 2) ? lAw : lBw) + ((t) & 1) * (256 * 64);    \
    const int _r = ((q) & 1) * 128;                                           \
    GL16(_g + (size_t)_r * IN_F,        _l + _r * 64);                        \
    GL16(_g + (size_t)(_r + 64) * IN_F, _l + (_r + 64) * 64);                 \
} while (0)

    // ---- fragment reads (swizzled chunk = (kk*4+g) ^ (row&7), row&7 == frow&7)
    const int frow = l & 15, g = l >> 4;
    const int cho0 = ((g ^ (frow & 7)) << 4);
    const int cho1 = (((4 + g) ^ (frow & 7)) << 4);
    const char* rowA = (const char*)&lA[0][wm * 128 + frow][0];
    const char* rowB = (const char*)&lB[0][wn * 64 + frow][0];
#define LDA_(p, m, kk) (*(const short8*)(rowA + (p) * 32768 + (m) * 2048 + ((kk) ? cho1 : cho0)))
#define LDB_(p, n, kk) (*(const short8*)(rowB + (p) * 32768 + (n) * 2048 + ((kk) ? cho1 : cho0)))

    f32x4 acc[8][4] = {};
    short8 ar[4][2], br[4][2];

#define QUAD(M0, N0) do {                                                     \
    __builtin_amdgcn_s_setprio(1);                                            \
    _Pragma("unroll") for (int mm = 0; mm < 4; ++mm)                          \
    _Pragma("unroll") for (int nn = 0; nn < 2; ++nn)                          \
    _Pragma("unroll") for (int kk = 0; kk < 2; ++kk)                          \
        acc[(M0) + mm][(N0) + nn] = __builtin_amdgcn_mfma_f32_16x16x32_bf16(  \
            ar[mm][kk], br[(N0) + nn][kk], acc[(M0) + mm][(N0) + nn], 0, 0, 0);\
    __builtin_amdgcn_s_setprio(0);                                            \
} while (0)

#define RD_A03_B01(p) do {                                                    \
    _Pragma("unroll") for (int mm = 0; mm < 4; ++mm) {                        \
        ar[mm][0] = LDA_(p, mm, 0); ar[mm][1] = LDA_(p, mm, 1); }             \
    br[0][0] = LDB_(p, 0, 0); br[0][1] = LDB_(p, 0, 1);                       \
    br[1][0] = LDB_(p, 1, 0); br[1][1] = LDB_(p, 1, 1);                       \
} while (0)
#define RD_B23(p) do {                                                        \
    br[2][0] = LDB_(p, 2, 0); br[2][1] = LDB_(p, 2, 1);                       \
    br[3][0] = LDB_(p, 3, 0); br[3][1] = LDB_(p, 3, 1);                       \
} while (0)
#define RD_A47(p) do {                                                        \
    _Pragma("unroll") for (int mm = 0; mm < 4; ++mm) {                        \
        ar[mm][0] = LDA_(p, 4 + mm, 0); ar[mm][1] = LDA_(p, 4 + mm, 1); }     \
} while (0)

    // prologue: stage tile0 fully + tile1 q0; VMW(2) -> tile0 complete
    STAGEQ(0, 0); STAGEQ(0, 1); STAGEQ(0, 2); STAGEQ(0, 3);
    STAGEQ(1, 0);
    VMW(2); BARRIER();

    // main loop: 2 K-tiles/iter (t=2i in buf0, t+1 in buf1); i = 0..30.
    // Staging cadence: A0:(t+1,q1) B0:(t+1,q2) C0:(t+1,q3) D0:(t+2,q0)+VMW(2)
    //                  A1:(t+2,q1) B1:(t+2,q2) C1:(t+2,q3) D1:(t+3,q0)+VMW(2)
    for (int i = 0; i < 31; ++i) {
        int t = 2 * i;
        // A0
        RD_A03_B01(0); STAGEQ(t + 1, 1); LGKM8();
        BARRIER(); QUAD(0, 0); BARRIER();
        // B0
        RD_B23(0); STAGEQ(t + 1, 2);
        BARRIER(); QUAD(0, 2); BARRIER();
        // C0
        RD_A47(0); STAGEQ(t + 1, 3);
        BARRIER(); QUAD(4, 2); BARRIER();
        // D0: stage (t+2,q0); VMW(2) retires tile t+1's 8 loads
        STAGEQ(t + 2, 0); VMW(2);
        BARRIER(); QUAD(4, 0); BARRIER();
        // A1
        RD_A03_B01(1); STAGEQ(t + 2, 1); LGKM8();
        BARRIER(); QUAD(0, 0); BARRIER();
        // B1
        RD_B23(1); STAGEQ(t + 2, 2);
        BARRIER(); QUAD(0, 2); BARRIER();
        // C1
        RD_A47(1); STAGEQ(t + 2, 3);
        BARRIER(); QUAD(4, 2); BARRIER();
        // D1: stage (t+3,q0); VMW(2) retires tile t+2's 8 loads
        STAGEQ(t + 3, 0); VMW(2);
        BARRIER(); QUAD(4, 0); BARRIER();
    }

    // peeled last pair (tiles 62 in buf0, 63 in buf1); finish staging 63
    RD_A03_B01(0); STAGEQ(63, 1); LGKM8();
    BARRIER(); QUAD(0, 0); BARRIER();
    RD_B23(0); STAGEQ(63, 2);
    BARRIER(); QUAD(0, 2); BARRIER();
    RD_A47(0); STAGEQ(63, 3);
    BARRIER(); QUAD(4, 2); BARRIER();
    VMW(0);                                  // drain: tile 63 complete
    BARRIER(); QUAD(4, 0); BARRIER();
    RD_A03_B01(1); BARRIER(); QUAD(0, 0); BARRIER();
    RD_B23(1);     BARRIER(); QUAD(0, 2); BARRIER();
    RD_A47(1);     BARRIER(); QUAD(4, 2); BARRIER();
    QUAD(4, 0);

    // epilogue: C/D layout col = lane&15, row = (lane>>4)*4 + jj
#pragma unroll
    for (int n = 0; n < 4; ++n) {
        int gcol = colBase + wn * 64 + n * 16 + frow;
        float bv = bias[gcol];
#pragma unroll
        for (int m = 0; m < 8; ++m) {
            int grow0 = rowBase + wm * 128 + m * 16 + g * 4;
#pragma unroll
            for (int jj = 0; jj < 4; ++jj)
                out[(size_t)(grow0 + jj) * OUT_F + gcol] = acc[m][n][jj] + bv;
        }
    }
}

// ---------- launch ----------
extern "C" void kernel_launch(void* const* d_in, const int* in_sizes, int n_in,
                              void* d_out, int out_size, void* d_ws, size_t ws_size,
                              hipStream_t stream) {
    const float* x         = (const float*)d_in[0];
    const int*   codes     = (const int*)d_in[1];
    const float* codebooks = (const float*)d_in[2];
    const float* scales    = (const float*)d_in[3];
    const float* bias      = (const float*)d_in[4];
    float* out = (float*)d_out;

    // workspace: Wq bf16 [OUT_F][IN_F], Xq bf16 [M_TOK][IN_F] = 157,286,400 B
    unsigned short* Wq = (unsigned short*)d_ws;
    unsigned short* Xq = (unsigned short*)((char*)d_ws + (size_t)OUT_F * IN_F * 2);

    k_dequant<<<NGRP / 256, 256, 0, stream>>>(codes, codebooks, scales, Wq);
    k_cvt<<<(M_TOK * IN_F / 8) / 256, 256, 0, stream>>>(x, Xq);
    // grid: (8192/256) * (11008/256) = 32 * 43 = 1376 blocks, 512 threads
    k_gemm<<<1376, 512, 0, stream>>>(Xq, Wq, bias, out);
}